// Round 12
// baseline (60.727 us; speedup 1.0000x reference)
//
#include <hip/hip_runtime.h>
#include <hip/hip_bf16.h>
#include <stdint.h>

typedef unsigned short u16;
typedef __attribute__((ext_vector_type(8))) short bf16x8;
typedef __attribute__((ext_vector_type(4))) float f32x4;
typedef __attribute__((ext_vector_type(2))) float f32x2;
typedef __attribute__((ext_vector_type(4))) unsigned int u32x4;
typedef __attribute__((ext_vector_type(2))) unsigned int u32x2;

#define NTOK 4096
#define NTHALF 16   // tiles (128 t2 each) per key-half

#if __has_builtin(__builtin_amdgcn_exp2f)
#define EXP2F __builtin_amdgcn_exp2f
#else
#define EXP2F exp2f
#endif

__device__ __forceinline__ f32x4 MFMA(bf16x8 a, bf16x8 b, f32x4 c) {
    return __builtin_amdgcn_mfma_f32_16x16x32_bf16(a, b, c, 0, 0, 0);
}

// packed f32->bf16 (D.lo = bf16(a), D.hi = bf16(b))
__device__ __forceinline__ uint32_t pk_bf16(float a, float b) {
    uint32_t d;
    asm("v_cvt_pk_bf16_f32 %0, %1, %2" : "=v"(d) : "v"(a), "v"(b));
    return d;
}

// truncation hi/lo split of 8 floats into two bf16x8 fragments
__device__ __forceinline__ void hilo_pack8(const float* v, bf16x8* h, bf16x8* l) {
    union { uint32_t u[4]; bf16x8 b; } H, L;
#pragma unroll
    for (int m = 0; m < 4; ++m) {
        const uint32_t ua = __float_as_uint(v[2*m]);
        const uint32_t ub = __float_as_uint(v[2*m+1]);
        const float la = v[2*m]   - __uint_as_float(ua & 0xffff0000u);
        const float lb = v[2*m+1] - __uint_as_float(ub & 0xffff0000u);
        H.u[m] = (ua >> 16) | (ub & 0xffff0000u);
        L.u[m] = (__float_as_uint(la) >> 16) | (__float_as_uint(lb) & 0xffff0000u);
    }
    *h = H.b; *l = L.b;
}

// ---------------------------------------------------------------------------
// k_qkv: QKV projection via MFMA (w,x hi/lo 3-term), then repack through LDS.
// (unchanged)
// ---------------------------------------------------------------------------
__global__ __launch_bounds__(256) void k_qkv(
    const float* __restrict__ x, const float* __restrict__ wqkv, const float* __restrict__ bqkv,
    u16* __restrict__ Qp, u16* __restrict__ Kp, u16* __restrict__ Vp)
{
    __shared__ float qt_lds[64 * 194];
    const int blk = blockIdx.x;
    const int b   = blk >> 6;
    const int tb  = (blk & 63) << 6;
    const int tid = threadIdx.x;
    const int lane = tid & 63;
    const int wv  = __builtin_amdgcn_readfirstlane(tid >> 6);
    const int r   = lane & 15;
    const int g   = lane >> 4;
    const int o0  = wv * 48;

    bf16x8 wh[3][2], wl[3][2];
#pragma unroll
    for (int oi = 0; oi < 3; ++oi)
#pragma unroll
        for (int ks = 0; ks < 2; ++ks) {
            const float* wp = wqkv + (size_t)(o0 + oi*16 + r) * 64 + ks*32 + g*8;
            float wv8[8];
            *(f32x4*)(wv8)     = *(const f32x4*)(wp);
            *(f32x4*)(wv8 + 4) = *(const f32x4*)(wp + 4);
            hilo_pack8(wv8, &wh[oi][ks], &wl[oi][ks]);
        }

    f32x4 acc[3][4];
#pragma unroll
    for (int oi = 0; oi < 3; ++oi)
#pragma unroll
        for (int tt = 0; tt < 4; ++tt) acc[oi][tt] = 0.f;

#pragma unroll
    for (int tt = 0; tt < 4; ++tt) {
        bf16x8 xh[2], xl[2];
#pragma unroll
        for (int ks = 0; ks < 2; ++ks) {
            float xv[8];
#pragma unroll
            for (int j = 0; j < 8; ++j)
                xv[j] = x[(size_t)(b*64 + ks*32 + g*8 + j) * NTOK + tb + tt*16 + r];
            hilo_pack8(xv, &xh[ks], &xl[ks]);
        }
#pragma unroll
        for (int oi = 0; oi < 3; ++oi) {
            f32x4 a = acc[oi][tt];
            a = MFMA(wh[oi][0], xh[0], a);
            a = MFMA(wh[oi][1], xh[1], a);
            a = MFMA(wl[oi][0], xh[0], a);
            a = MFMA(wl[oi][1], xh[1], a);
            a = MFMA(wh[oi][0], xl[0], a);
            a = MFMA(wh[oi][1], xl[1], a);
            acc[oi][tt] = a;
        }
    }

#pragma unroll
    for (int oi = 0; oi < 3; ++oi)
#pragma unroll
        for (int tt = 0; tt < 4; ++tt)
#pragma unroll
            for (int i = 0; i < 4; ++i)
                qt_lds[(tt*16 + r) * 194 + o0 + oi*16 + g*4 + i] = acc[oi][tt][i];
    __syncthreads();

    const float SC = 0.18033688011112042f;  // (1/8) * log2(e)

    {
        const int t = tid >> 2, c0 = (tid & 3) * 16;
        float v[16], bq[16];
#pragma unroll
        for (int m = 0; m < 8; ++m)
            *(f32x2*)(v + 2*m) = *(const f32x2*)&qt_lds[t*194 + c0 + 2*m];
#pragma unroll
        for (int m = 0; m < 4; ++m)
            *(f32x4*)(bq + 4*m) = *(const f32x4*)(bqkv + c0 + 4*m);
        u32x4 P0, P1;
#pragma unroll
        for (int m = 0; m < 4; ++m) {
            P0[m] = pk_bf16((v[2*m]   + bq[2*m]  ) * SC, (v[2*m+1] + bq[2*m+1]) * SC);
            P1[m] = pk_bf16((v[8+2*m] + bq[8+2*m]) * SC, (v[9+2*m] + bq[9+2*m]) * SC);
        }
        size_t base = ((size_t)(b * NTOK + tb + t)) * 64 + c0;
        *(u32x4*)(Qp + base)     = P0;
        *(u32x4*)(Qp + base + 8) = P1;
    }

#pragma unroll
    for (int uu = 0; uu < 2; ++uu) {
        const int u  = tid * 2 + uu;
        const int t  = u >> 3;
        const int ks = (u >> 2) & 1;
        const int gk = u & 3;
        const int cb0 = 64 + ks*32 + gk*8;
        float v[8];
#pragma unroll
        for (int m = 0; m < 4; ++m)
            *(f32x2*)(v + 2*m) = *(const f32x2*)&qt_lds[t*194 + cb0 + 2*m];
        u32x4 P;
#pragma unroll
        for (int m = 0; m < 4; ++m)
            P[m] = pk_bf16(v[2*m] + bqkv[cb0 + 2*m], v[2*m+1] + bqkv[cb0 + 2*m+1]);
        const int tg = tb + t;
        size_t kbase = (size_t)b * 262144 + ((size_t)(tg >> 4) * 2 + ks) * 512 + gk*128 + (t & 15) * 8;
        *(u32x4*)(Kp + kbase) = P;
    }

    {
        const int cb = (tid >> 4) & 3;
        const int r2 = tid & 15;
        const float bv = bqkv[128 + cb*16 + r2];
        const int T = (blk & 63) >> 1;
        const int halfb = blk & 1;
#pragma unroll
        for (int m = 0; m < 4; ++m) {
            const int tq = m * 4 + (tid >> 6);
            float v[4];
#pragma unroll
            for (int jj = 0; jj < 4; ++jj)
                v[jj] = qt_lds[(tq*4 + jj)*194 + 128 + cb*16 + r2] + bv;
            const int t = tq * 4;
            const int wtr = halfb*2 + (t >> 5);
            const int sti = (t >> 4) & 1;
            const int g2  = (t >> 2) & 3;
            u32x2 W;
            W[0] = pk_bf16(v[0], v[1]);
            W[1] = pk_bf16(v[2], v[3]);
            size_t vbase = (size_t)b * 262144 +
                           (((size_t)T * 4 + wtr) * 4 + cb) * 512 + (g2*16 + r2) * 8 + sti * 4;
            *(u32x2*)(Vp + vbase) = W;
        }
    }
}

// ---------------------------------------------------------------------------
// k_attn: flash attention, fixed-shift softmax, register-only barrier-free
// main loop. KEY-HALF SPLIT: grid 1024 = 8 b x 64 qt x 2 key-halves; each
// block: 64 Q-rows x 2048 keys (16 tiles). Bytes stay 512 MB while grid
// doubles -> 3-4 blocks/CU -> 12-16 waves/CU (needs combined regs <= ~170,
// hence: no K double-buffer, l via VALU lane-partials not MFMA-ONES).
// Writes raw per-half (O,l) partials; k_out merges (sums are exact under
// fixed-shift softmax), normalizes, and does the fused out-projection.
// ---------------------------------------------------------------------------
__global__ __launch_bounds__(256, 3) void k_attn(
    const u16* __restrict__ Qp, const u16* __restrict__ Kp, const u16* __restrict__ Vp,
    float* __restrict__ Opart, float* __restrict__ Lpart)
{
    __shared__ float otbuf[2][64 * 68];   // stride 68 -> 16B-aligned rows
    __shared__ float larr[4][64];
    const int hw  = blockIdx.x;
    const int b   = hw & 7;        // batch -> XCD pinning
    const int rest = hw >> 3;      // 0..127
    const int qt  = rest >> 1;     // 0..63
    const int kh  = rest & 1;      // key-half
    const int tid = threadIdx.x;
    const int lane = tid & 63;
    const int wt2 = tid >> 6;      // t2-slice 0..3
    const int r   = lane & 15;
    const int g   = lane >> 4;
    const int row0 = qt * 64;

    // Q fragments (B operand), rows row0 + rt*16 + r, rt = 0..3
    bf16x8 qh[4][2];
#pragma unroll
    for (int rt = 0; rt < 4; ++rt) {
        const size_t qoff = ((size_t)(b * NTOK + row0 + rt*16 + r)) * 64 + g * 8;
        qh[rt][0] = *(const bf16x8*)(Qp + qoff);
        qh[rt][1] = *(const bf16x8*)(Qp + qoff + 32);
    }

    // running per-wave K/V pointers for this key-half (tile stride 8192 elems)
    const u16* kptr = Kp + (size_t)b * 262144 + (size_t)kh * NTHALF * 8192 + wt2 * 2048 + (size_t)lane * 8;
    const u16* vptr = Vp + (size_t)b * 262144 + (size_t)kh * NTHALF * 8192 + wt2 * 2048 + (size_t)lane * 8;

    f32x4 oacc[4][4];
#pragma unroll
    for (int rt = 0; rt < 4; ++rt)
#pragma unroll
        for (int cb = 0; cb < 4; ++cb) oacc[rt][cb] = 0.f;
    float lpart[4] = {0.f, 0.f, 0.f, 0.f};

    for (int T = 0; T < NTHALF; ++T) {
        bf16x8 kc[2][2];
#pragma unroll
        for (int sti = 0; sti < 2; ++sti)
#pragma unroll
            for (int ks = 0; ks < 2; ++ks)
                kc[sti][ks] = *(const bf16x8*)(kptr + sti*1024 + ks*512);
        bf16x8 vf[4];
#pragma unroll
        for (int cb = 0; cb < 4; ++cb)
            vf[cb] = *(const bf16x8*)(vptr + cb*512);
        kptr += 8192;
        vptr += 8192;

        // QK^T: row-tiles in pairs (cap live S registers)
#pragma unroll
        for (int rp = 0; rp < 2; ++rp) {
            f32x4 s[2][2];
            __builtin_amdgcn_s_setprio(1);
#pragma unroll
            for (int rr = 0; rr < 2; ++rr)
#pragma unroll
                for (int sti = 0; sti < 2; ++sti) {
                    f32x4 a = {0.f, 0.f, 0.f, 0.f};
                    a = MFMA(kc[sti][0], qh[rp*2 + rr][0], a);
                    a = MFMA(kc[sti][1], qh[rp*2 + rr][1], a);
                    s[rr][sti] = a;
                }
            __builtin_amdgcn_s_setprio(0);

#pragma unroll
            for (int rr = 0; rr < 2; ++rr) {
                const int rt = rp*2 + rr;
                float p[8];
#pragma unroll
                for (int sti = 0; sti < 2; ++sti)
#pragma unroll
                    for (int i = 0; i < 4; ++i)
                        p[sti*4 + i] = EXP2F(s[rr][sti][i]);
                lpart[rt] += ((p[0]+p[1]) + (p[2]+p[3])) + ((p[4]+p[5]) + (p[6]+p[7]));
                union { uint32_t u[4]; bf16x8 b; } PA;
#pragma unroll
                for (int m = 0; m < 4; ++m) PA.u[m] = pk_bf16(p[2*m], p[2*m+1]);
                __builtin_amdgcn_s_setprio(1);
#pragma unroll
                for (int cb = 0; cb < 4; ++cb)
                    oacc[rt][cb] = MFMA(PA.b, vf[cb], oacc[rt][cb]);
                __builtin_amdgcn_s_setprio(0);
            }
        }
    }

    // ---- epilogue: reduce l across g-groups; merge O across the 4 waves ----
#pragma unroll
    for (int rt = 0; rt < 4; ++rt) {
        float v = lpart[rt];
        v += __shfl_xor(v, 16);
        v += __shfl_xor(v, 32);
        lpart[rt] = v;           // lanes with same r now hold the row sum
    }
    if (lane < 16) {
#pragma unroll
        for (int rt = 0; rt < 4; ++rt)
            larr[wt2][rt*16 + lane] = lpart[rt];
    }

    if (wt2 < 2) {
        float* ob = otbuf[wt2];
#pragma unroll
        for (int rt = 0; rt < 4; ++rt)
#pragma unroll
            for (int cb = 0; cb < 4; ++cb)
#pragma unroll
                for (int i = 0; i < 4; ++i)
                    ob[(rt*16 + g*4 + i)*68 + cb*16 + r] = oacc[rt][cb][i];
    }
    __syncthreads();
    if (wt2 >= 2) {
        float* ob = otbuf[wt2 - 2];
#pragma unroll
        for (int rt = 0; rt < 4; ++rt)
#pragma unroll
            for (int cb = 0; cb < 4; ++cb)
#pragma unroll
                for (int i = 0; i < 4; ++i)
                    ob[(rt*16 + g*4 + i)*68 + cb*16 + r] += oacc[rt][cb][i];
    }
    __syncthreads();

    // ---- store raw (O, l) partials for this key-half ----
    float* OB = Opart + (((size_t)(b * 64 + qt)) * 2 + kh) * 4096;
    {
        const int row = tid >> 2, c0 = (tid & 3) * 16;
#pragma unroll
        for (int m = 0; m < 4; ++m) {
            f32x4 v0 = *(const f32x4*)&otbuf[0][row*68 + c0 + 4*m];
            f32x4 v1 = *(const f32x4*)&otbuf[1][row*68 + c0 + 4*m];
            *(f32x4*)&OB[row*64 + c0 + 4*m] = v0 + v1;
        }
    }
    if (tid < 64) {
        Lpart[(((size_t)(b * 64 + qt)) * 2 + kh) * 64 + tid] =
            larr[0][tid] + larr[1][tid] + larr[2][tid] + larr[3][tid];
    }
}

// ---------------------------------------------------------------------------
// k_out: merge the two key-half partials (exact sums under fixed-shift
// softmax), normalize by total l, fused out-projection + bias + residual.
// grid 512 = 8 b x 64 qt; block 256 = 4 waves; wave wt2 handles rows wt2*16+r.
// ---------------------------------------------------------------------------
__global__ __launch_bounds__(256) void k_out(
    const float* __restrict__ Opart, const float* __restrict__ Lpart,
    const float* __restrict__ wout, const float* __restrict__ bout,
    const float* __restrict__ x, float* __restrict__ out)
{
    const int hw  = blockIdx.x;
    const int b   = hw & 7;
    const int qt  = hw >> 3;
    const int tid = threadIdx.x;
    const int lane = tid & 63;
    const int wt2 = tid >> 6;
    const int r   = lane & 15;
    const int g   = lane >> 4;
    const int row0 = qt * 64;

    const float* O0 = Opart + ((size_t)(b * 64 + qt)) * 2 * 4096;
    const float* O1 = O0 + 4096;
    const float* L  = Lpart + ((size_t)(b * 64 + qt)) * 2 * 64;

    const int orow = wt2*16 + r;
    const float inv = 1.0f / (L[orow] + L[64 + orow]);

    bf16x8 oh_[2], ol_[2];
#pragma unroll
    for (int ks = 0; ks < 2; ++ks) {
        float ov[8];
        f32x4 a0 = *(const f32x4*)&O0[orow*64 + ks*32 + g*8];
        f32x4 a1 = *(const f32x4*)&O0[orow*64 + ks*32 + g*8 + 4];
        f32x4 b0 = *(const f32x4*)&O1[orow*64 + ks*32 + g*8];
        f32x4 b1 = *(const f32x4*)&O1[orow*64 + ks*32 + g*8 + 4];
#pragma unroll
        for (int i = 0; i < 4; ++i) {
            ov[i]     = (a0[i] + b0[i]) * inv;
            ov[4 + i] = (a1[i] + b1[i]) * inv;
        }
        hilo_pack8(ov, &oh_[ks], &ol_[ks]);
    }
#pragma unroll
    for (int ot = 0; ot < 4; ++ot) {
        bf16x8 wh2[2], wl2[2];
#pragma unroll
        for (int ks = 0; ks < 2; ++ks) {
            const float* wp = wout + (size_t)(ot*16 + r) * 64 + ks*32 + g*8;
            float wv8[8];
            *(f32x4*)(wv8)     = *(const f32x4*)(wp);
            *(f32x4*)(wv8 + 4) = *(const f32x4*)(wp + 4);
            hilo_pack8(wv8, &wh2[ks], &wl2[ks]);
        }
        f32x4 a = {0.f, 0.f, 0.f, 0.f};
        a = MFMA(wh2[0], oh_[0], a);
        a = MFMA(wh2[1], oh_[1], a);
        a = MFMA(wl2[0], oh_[0], a);
        a = MFMA(wl2[1], oh_[1], a);
        a = MFMA(wh2[0], ol_[0], a);
        a = MFMA(wh2[1], ol_[1], a);
#pragma unroll
        for (int i = 0; i < 4; ++i) {
            const int oo = ot*16 + g*4 + i;
            const size_t xi = ((size_t)(b*64 + oo)) * NTOK + row0 + wt2*16 + r;
            out[xi] = a[i] + bout[oo] + x[xi];
        }
    }
}

extern "C" void kernel_launch(void* const* d_in, const int* in_sizes, int n_in,
                              void* d_out, int out_size, void* d_ws, size_t ws_size,
                              hipStream_t stream)
{
    (void)in_sizes; (void)n_in; (void)out_size; (void)ws_size;
    const float* x    = (const float*)d_in[0];
    const float* wqkv = (const float*)d_in[1];
    const float* bqkv = (const float*)d_in[2];
    const float* wout = (const float*)d_in[3];
    const float* bout = (const float*)d_in[4];
    float* out = (float*)d_out;

    char* ws = (char*)d_ws;
    const size_t MB = 1024 * 1024;
    u16*   Qp    = (u16*)(ws);
    u16*   Kp    = (u16*)(ws + 4 * MB);
    u16*   Vp    = (u16*)(ws + 8 * MB);
    float* Opart = (float*)(ws + 12 * MB);   // 16 MB
    float* Lpart = (float*)(ws + 29 * MB);   // 256 KB

    k_qkv<<<512, 256, 0, stream>>>(x, wqkv, bqkv, Qp, Kp, Vp);
    k_attn<<<1024, 256, 0, stream>>>(Qp, Kp, Vp, Opart, Lpart);
    k_out<<<512, 256, 0, stream>>>(Opart, Lpart, wout, bout, x, out);
}

// Round 14
// 54.150 us; speedup vs baseline: 1.1215x; 1.1215x over previous
//
#include <hip/hip_runtime.h>
#include <hip/hip_bf16.h>
#include <stdint.h>

typedef unsigned short u16;
typedef __attribute__((ext_vector_type(8))) short bf16x8;
typedef __attribute__((ext_vector_type(4))) float f32x4;
typedef __attribute__((ext_vector_type(2))) float f32x2;
typedef __attribute__((ext_vector_type(4))) unsigned int u32x4;
typedef __attribute__((ext_vector_type(2))) unsigned int u32x2;

#define NTOK 4096
#define NT32 32   // 4096 / 128 t2-tiles

#if __has_builtin(__builtin_amdgcn_exp2f)
#define EXP2F __builtin_amdgcn_exp2f
#else
#define EXP2F exp2f
#endif

__device__ __forceinline__ f32x4 MFMA(bf16x8 a, bf16x8 b, f32x4 c) {
    return __builtin_amdgcn_mfma_f32_16x16x32_bf16(a, b, c, 0, 0, 0);
}

// packed f32->bf16 (D.lo = bf16(a), D.hi = bf16(b))
__device__ __forceinline__ uint32_t pk_bf16(float a, float b) {
    uint32_t d;
    asm("v_cvt_pk_bf16_f32 %0, %1, %2" : "=v"(d) : "v"(a), "v"(b));
    return d;
}

// truncation hi/lo split of 8 floats into two bf16x8 fragments
__device__ __forceinline__ void hilo_pack8(const float* v, bf16x8* h, bf16x8* l) {
    union { uint32_t u[4]; bf16x8 b; } H, L;
#pragma unroll
    for (int m = 0; m < 4; ++m) {
        const uint32_t ua = __float_as_uint(v[2*m]);
        const uint32_t ub = __float_as_uint(v[2*m+1]);
        const float la = v[2*m]   - __uint_as_float(ua & 0xffff0000u);
        const float lb = v[2*m+1] - __uint_as_float(ub & 0xffff0000u);
        H.u[m] = (ua >> 16) | (ub & 0xffff0000u);
        L.u[m] = (__float_as_uint(la) >> 16) | (__float_as_uint(lb) & 0xffff0000u);
    }
    *h = H.b; *l = L.b;
}

// ---------------------------------------------------------------------------
// k_qkv: QKV projection via MFMA (w,x hi/lo 3-term), then repack through LDS.
// (unchanged — proven since R4)
// ---------------------------------------------------------------------------
__global__ __launch_bounds__(256) void k_qkv(
    const float* __restrict__ x, const float* __restrict__ wqkv, const float* __restrict__ bqkv,
    u16* __restrict__ Qp, u16* __restrict__ Kp, u16* __restrict__ Vp)
{
    __shared__ float qt_lds[64 * 194];
    const int blk = blockIdx.x;
    const int b   = blk >> 6;
    const int tb  = (blk & 63) << 6;
    const int tid = threadIdx.x;
    const int lane = tid & 63;
    const int wv  = __builtin_amdgcn_readfirstlane(tid >> 6);
    const int r   = lane & 15;
    const int g   = lane >> 4;
    const int o0  = wv * 48;

    bf16x8 wh[3][2], wl[3][2];
#pragma unroll
    for (int oi = 0; oi < 3; ++oi)
#pragma unroll
        for (int ks = 0; ks < 2; ++ks) {
            const float* wp = wqkv + (size_t)(o0 + oi*16 + r) * 64 + ks*32 + g*8;
            float wv8[8];
            *(f32x4*)(wv8)     = *(const f32x4*)(wp);
            *(f32x4*)(wv8 + 4) = *(const f32x4*)(wp + 4);
            hilo_pack8(wv8, &wh[oi][ks], &wl[oi][ks]);
        }

    f32x4 acc[3][4];
#pragma unroll
    for (int oi = 0; oi < 3; ++oi)
#pragma unroll
        for (int tt = 0; tt < 4; ++tt) acc[oi][tt] = 0.f;

#pragma unroll
    for (int tt = 0; tt < 4; ++tt) {
        bf16x8 xh[2], xl[2];
#pragma unroll
        for (int ks = 0; ks < 2; ++ks) {
            float xv[8];
#pragma unroll
            for (int j = 0; j < 8; ++j)
                xv[j] = x[(size_t)(b*64 + ks*32 + g*8 + j) * NTOK + tb + tt*16 + r];
            hilo_pack8(xv, &xh[ks], &xl[ks]);
        }
#pragma unroll
        for (int oi = 0; oi < 3; ++oi) {
            f32x4 a = acc[oi][tt];
            a = MFMA(wh[oi][0], xh[0], a);
            a = MFMA(wh[oi][1], xh[1], a);
            a = MFMA(wl[oi][0], xh[0], a);
            a = MFMA(wl[oi][1], xh[1], a);
            a = MFMA(wh[oi][0], xl[0], a);
            a = MFMA(wh[oi][1], xl[1], a);
            acc[oi][tt] = a;
        }
    }

#pragma unroll
    for (int oi = 0; oi < 3; ++oi)
#pragma unroll
        for (int tt = 0; tt < 4; ++tt)
#pragma unroll
            for (int i = 0; i < 4; ++i)
                qt_lds[(tt*16 + r) * 194 + o0 + oi*16 + g*4 + i] = acc[oi][tt][i];
    __syncthreads();

    const float SC = 0.18033688011112042f;  // (1/8) * log2(e)

    {
        const int t = tid >> 2, c0 = (tid & 3) * 16;
        float v[16], bq[16];
#pragma unroll
        for (int m = 0; m < 8; ++m)
            *(f32x2*)(v + 2*m) = *(const f32x2*)&qt_lds[t*194 + c0 + 2*m];
#pragma unroll
        for (int m = 0; m < 4; ++m)
            *(f32x4*)(bq + 4*m) = *(const f32x4*)(bqkv + c0 + 4*m);
        u32x4 P0, P1;
#pragma unroll
        for (int m = 0; m < 4; ++m) {
            P0[m] = pk_bf16((v[2*m]   + bq[2*m]  ) * SC, (v[2*m+1] + bq[2*m+1]) * SC);
            P1[m] = pk_bf16((v[8+2*m] + bq[8+2*m]) * SC, (v[9+2*m] + bq[9+2*m]) * SC);
        }
        size_t base = ((size_t)(b * NTOK + tb + t)) * 64 + c0;
        *(u32x4*)(Qp + base)     = P0;
        *(u32x4*)(Qp + base + 8) = P1;
    }

#pragma unroll
    for (int uu = 0; uu < 2; ++uu) {
        const int u  = tid * 2 + uu;
        const int t  = u >> 3;
        const int ks = (u >> 2) & 1;
        const int gk = u & 3;
        const int cb0 = 64 + ks*32 + gk*8;
        float v[8];
#pragma unroll
        for (int m = 0; m < 4; ++m)
            *(f32x2*)(v + 2*m) = *(const f32x2*)&qt_lds[t*194 + cb0 + 2*m];
        u32x4 P;
#pragma unroll
        for (int m = 0; m < 4; ++m)
            P[m] = pk_bf16(v[2*m] + bqkv[cb0 + 2*m], v[2*m+1] + bqkv[cb0 + 2*m+1]);
        const int tg = tb + t;
        size_t kbase = (size_t)b * 262144 + ((size_t)(tg >> 4) * 2 + ks) * 512 + gk*128 + (t & 15) * 8;
        *(u32x4*)(Kp + kbase) = P;
    }

    {
        const int cb = (tid >> 4) & 3;
        const int r2 = tid & 15;
        const float bv = bqkv[128 + cb*16 + r2];
        const int T = (blk & 63) >> 1;
        const int halfb = blk & 1;
#pragma unroll
        for (int m = 0; m < 4; ++m) {
            const int tq = m * 4 + (tid >> 6);
            float v[4];
#pragma unroll
            for (int jj = 0; jj < 4; ++jj)
                v[jj] = qt_lds[(tq*4 + jj)*194 + 128 + cb*16 + r2] + bv;
            const int t = tq * 4;
            const int wtr = halfb*2 + (t >> 5);
            const int sti = (t >> 4) & 1;
            const int g2  = (t >> 2) & 3;
            u32x2 W;
            W[0] = pk_bf16(v[0], v[1]);
            W[1] = pk_bf16(v[2], v[3]);
            size_t vbase = (size_t)b * 262144 +
                           (((size_t)T * 4 + wtr) * 4 + cb) * 512 + (g2*16 + r2) * 8 + sti * 4;
            *(u32x2*)(Vp + vbase) = W;
        }
    }
}

// ---------------------------------------------------------------------------
// k_attn: R11's proven kernel (41.8 us) + V A/B register double-buffer
// (the R8-proven K+V dbuf pattern, at the permissive (256,2) bound).
// grid 512 = 8 b x 64 Q-tiles (64 rows); block 256 = 4 waves, each wave:
// ALL 64 Q-rows x a 32-t2 slice of each 128-t2 tile. Fixed-shift softmax;
// row-sum l via MFMA-ONES; fused out-projection + residual epilogue.
// ---------------------------------------------------------------------------
__global__ __launch_bounds__(256, 2) void k_attn(
    const u16* __restrict__ Qp, const u16* __restrict__ Kp, const u16* __restrict__ Vp,
    const float* __restrict__ wout, const float* __restrict__ bout,
    const float* __restrict__ x, float* __restrict__ out)
{
    __shared__ float larr[4][64];
    __shared__ float otbuf[2][64 * 67];
    const int hw  = blockIdx.x;
    const int b   = hw & 7;        // batch -> XCD pinning
    const int qt  = hw >> 3;       // 0..63
    const int tid = threadIdx.x;
    const int lane = tid & 63;
    const int wt2 = tid >> 6;      // t2-slice 0..3
    const int r   = lane & 15;
    const int g   = lane >> 4;
    const int row0 = qt * 64;

    // Q fragments (B operand), rows row0 + rt*16 + r, rt = 0..3
    bf16x8 qh[4][2];
#pragma unroll
    for (int rt = 0; rt < 4; ++rt) {
        const size_t qoff = ((size_t)(b * NTOK + row0 + rt*16 + r)) * 64 + g * 8;
        qh[rt][0] = *(const bf16x8*)(Qp + qoff);
        qh[rt][1] = *(const bf16x8*)(Qp + qoff + 32);
    }

    // per-wave K/V fragment bases (tile stride 8192 elems = 16 KB)
    const u16* kbase = Kp + (size_t)b * 262144 + wt2 * 2048 + (size_t)lane * 8;
    const u16* vbase = Vp + (size_t)b * 262144 + wt2 * 2048 + (size_t)lane * 8;

    // ones B-fragment for row-sum MFMA
    bf16x8 ONES;
#pragma unroll
    for (int j = 0; j < 8; ++j) ONES[j] = (short)0x3F80;

    f32x4 oacc[4][4];
#pragma unroll
    for (int rt = 0; rt < 4; ++rt)
#pragma unroll
        for (int cb = 0; cb < 4; ++cb) oacc[rt][cb] = 0.f;
    f32x4 lacc[4];
#pragma unroll
    for (int rt = 0; rt < 4; ++rt) lacc[rt] = 0.f;

    // preload K and V for tiles 0 (A) and 1 (B)
    bf16x8 kA[2][2], kB[2][2], vA[4], vB[4];
#pragma unroll
    for (int sti = 0; sti < 2; ++sti)
#pragma unroll
        for (int ks = 0; ks < 2; ++ks) {
            kA[sti][ks] = *(const bf16x8*)(kbase + (size_t)0*8192 + sti*1024 + ks*512);
            kB[sti][ks] = *(const bf16x8*)(kbase + (size_t)1*8192 + sti*1024 + ks*512);
        }
#pragma unroll
    for (int cb = 0; cb < 4; ++cb) {
        vA[cb] = *(const bf16x8*)(vbase + (size_t)0*8192 + cb*512);
        vB[cb] = *(const bf16x8*)(vbase + (size_t)1*8192 + cb*512);
    }

    auto halfrt = [&](bf16x8 (&kb)[2][2], bf16x8 (&vf)[4], int rt0) {
        // QK^T for row-tiles rt0, rt0+1 (8 MFMA)
        f32x4 s[2][2];
        __builtin_amdgcn_s_setprio(1);
#pragma unroll
        for (int rr = 0; rr < 2; ++rr)
#pragma unroll
            for (int sti = 0; sti < 2; ++sti) {
                f32x4 a = {0.f, 0.f, 0.f, 0.f};
                a = MFMA(kb[sti][0], qh[rt0 + rr][0], a);
                a = MFMA(kb[sti][1], qh[rt0 + rr][1], a);
                s[rr][sti] = a;
            }
        __builtin_amdgcn_s_setprio(0);

        // fixed-shift softmax + PV + l for the pair
#pragma unroll
        for (int rr = 0; rr < 2; ++rr) {
            const int rt = rt0 + rr;
            float p[8];
#pragma unroll
            for (int sti = 0; sti < 2; ++sti)
#pragma unroll
                for (int i = 0; i < 4; ++i)
                    p[sti*4 + i] = EXP2F(s[rr][sti][i]);
            union { uint32_t u[4]; bf16x8 b; } PA;
#pragma unroll
            for (int m = 0; m < 4; ++m) PA.u[m] = pk_bf16(p[2*m], p[2*m+1]);
            __builtin_amdgcn_s_setprio(1);
#pragma unroll
            for (int cb = 0; cb < 4; ++cb)
                oacc[rt][cb] = MFMA(PA.b, vf[cb], oacc[rt][cb]);
            lacc[rt] = MFMA(PA.b, ONES, lacc[rt]);
            __builtin_amdgcn_s_setprio(0);
        }
    };

    auto body = [&](bf16x8 (&kb)[2][2], bf16x8 (&vb)[4], int Tp) {
        halfrt(kb, vb, 0);
        halfrt(kb, vb, 2);

        // prefetch K and V for tile Tp into the register sets just consumed
        // (issued here, consumed one full body later -> latency hidden)
        const u16* kp = kbase + (size_t)Tp * 8192;
        const u16* vp = vbase + (size_t)Tp * 8192;
#pragma unroll
        for (int sti = 0; sti < 2; ++sti)
#pragma unroll
            for (int ks = 0; ks < 2; ++ks)
                kb[sti][ks] = *(const bf16x8*)(kp + sti*1024 + ks*512);
#pragma unroll
        for (int cb = 0; cb < 4; ++cb)
            vb[cb] = *(const bf16x8*)(vp + cb*512);
    };

    for (int T = 0; T < NT32; T += 2) {
        const int TpA = (T + 2 < NT32) ? T + 2 : NT32 - 1;
        const int TpB = (T + 3 < NT32) ? T + 3 : NT32 - 1;
        body(kA, vA, TpA);
        body(kB, vB, TpB);
    }

    // ---- epilogue: 4-way slice merge (plain sums; shift-exact softmax) ----
    if (r == 0) {
#pragma unroll
        for (int rt = 0; rt < 4; ++rt)
#pragma unroll
            for (int i = 0; i < 4; ++i)
                larr[wt2][rt*16 + g*4 + i] = lacc[rt][i];
    }

    // accumulate raw O partials (64 rows x 64 cols): wt2 0/1 write, 2/3 add
    if (wt2 < 2) {
        float* ob = otbuf[wt2];
#pragma unroll
        for (int rt = 0; rt < 4; ++rt)
#pragma unroll
            for (int cb = 0; cb < 4; ++cb)
#pragma unroll
                for (int i = 0; i < 4; ++i)
                    ob[(rt*16 + g*4 + i)*67 + cb*16 + r] = oacc[rt][cb][i];
    }
    __syncthreads();
    if (wt2 >= 2) {
        float* ob = otbuf[wt2 - 2];
#pragma unroll
        for (int rt = 0; rt < 4; ++rt)
#pragma unroll
            for (int cb = 0; cb < 4; ++cb)
#pragma unroll
                for (int i = 0; i < 4; ++i)
                    ob[(rt*16 + g*4 + i)*67 + cb*16 + r] += oacc[rt][cb][i];
    }
    __syncthreads();

    // ---- fused out-projection + bias + residual ----
    // wave wt2 handles block-local token rows wt2*16 + r, all 64 outputs
    const int orow = wt2*16 + r;
    const float inv = 1.0f / (larr[0][orow] + larr[1][orow] + larr[2][orow] + larr[3][orow]);
    bf16x8 oh_[2], ol_[2];
#pragma unroll
    for (int ks = 0; ks < 2; ++ks) {
        float ov[8];
#pragma unroll
        for (int j = 0; j < 8; ++j) {
            const int idx = orow*67 + ks*32 + g*8 + j;
            ov[j] = (otbuf[0][idx] + otbuf[1][idx]) * inv;
        }
        hilo_pack8(ov, &oh_[ks], &ol_[ks]);
    }
#pragma unroll
    for (int ot = 0; ot < 4; ++ot) {
        bf16x8 wh2[2], wl2[2];
#pragma unroll
        for (int ks = 0; ks < 2; ++ks) {
            const float* wp = wout + (size_t)(ot*16 + r) * 64 + ks*32 + g*8;
            float wv8[8];
            *(f32x4*)(wv8)     = *(const f32x4*)(wp);
            *(f32x4*)(wv8 + 4) = *(const f32x4*)(wp + 4);
            hilo_pack8(wv8, &wh2[ks], &wl2[ks]);
        }
        f32x4 a = {0.f, 0.f, 0.f, 0.f};
        a = MFMA(wh2[0], oh_[0], a);
        a = MFMA(wh2[1], oh_[1], a);
        a = MFMA(wl2[0], oh_[0], a);
        a = MFMA(wl2[1], oh_[1], a);
        a = MFMA(wh2[0], ol_[0], a);
        a = MFMA(wh2[1], ol_[1], a);
#pragma unroll
        for (int i = 0; i < 4; ++i) {
            const int oo = ot*16 + g*4 + i;
            const size_t xi = ((size_t)(b*64 + oo)) * NTOK + row0 + wt2*16 + r;
            out[xi] = a[i] + bout[oo] + x[xi];
        }
    }
}

extern "C" void kernel_launch(void* const* d_in, const int* in_sizes, int n_in,
                              void* d_out, int out_size, void* d_ws, size_t ws_size,
                              hipStream_t stream)
{
    (void)in_sizes; (void)n_in; (void)out_size; (void)ws_size;
    const float* x    = (const float*)d_in[0];
    const float* wqkv = (const float*)d_in[1];
    const float* bqkv = (const float*)d_in[2];
    const float* wout = (const float*)d_in[3];
    const float* bout = (const float*)d_in[4];
    float* out = (float*)d_out;

    char* ws = (char*)d_ws;
    const size_t MB = 1024 * 1024;
    u16* Qp = (u16*)(ws);
    u16* Kp = (u16*)(ws + 4 * MB);
    u16* Vp = (u16*)(ws + 8 * MB);

    k_qkv<<<512, 256, 0, stream>>>(x, wqkv, bqkv, Qp, Kp, Vp);
    k_attn<<<512, 256, 0, stream>>>(Qp, Kp, Vp, wout, bout, x, out);
}